// Round 1
// baseline (234.917 us; speedup 1.0000x reference)
//
#include <hip/hip_runtime.h>

// Problem constants (from reference)
constexpr int B        = 2;
constexpr int N_IN     = 262144;
constexpr int D        = 32;
constexpr int N_OUT    = 65536;
constexpr int K        = 4;
constexpr int NK       = 9;
constexpr int P        = B * N_OUT * K;   // 524288 output points
constexpr int PK_BITS  = 18;              // N_OUT*K = 2^18 points per batch

// 8 lanes per point, each lane handles 4 channels (float4).
// Block 256 threads = 32 points. Grid = P/32 = 16384 blocks.
__global__ __launch_bounds__(256) void projection_kernel(
    const float* __restrict__ x,          // (B, N_IN, D)
    const float* __restrict__ coords_in,  // (2, B, N_IN)
    const float* __restrict__ coords_out, // (2, B, N_OUT, K) == (2, P)
    const float* __restrict__ sigma,      // (D,)
    const int*   __restrict__ nidx,       // (B, N_OUT, K, NK) == (P, NK)
    float*       __restrict__ out)        // (B, N_OUT*K, D) == (P, D)
{
    const int tid   = blockIdx.x * 256 + threadIdx.x;
    const int point = tid >> 3;       // one point per 8 lanes
    const int q     = tid & 7;        // channel quad: d = 4q .. 4q+3

    const int b     = point >> PK_BITS;
    const int cbase = b * N_IN;

    // coords_out[c][point], c in {0,1}: flat c*P + point (broadcast across 8 lanes)
    const float cox = coords_out[point];
    const float coy = coords_out[P + point];

    // per-channel 1/(2 sigma^2)
    const float4 sg = *reinterpret_cast<const float4*>(sigma + q * 4);
    const float s0 = 1.0f / (2.0f * sg.x * sg.x);
    const float s1 = 1.0f / (2.0f * sg.y * sg.y);
    const float s2 = 1.0f / (2.0f * sg.z * sg.z);
    const float s3 = 1.0f / (2.0f * sg.w * sg.w);

    float4 num = make_float4(0.f, 0.f, 0.f, 0.f);
    float4 den = make_float4(0.f, 0.f, 0.f, 0.f);

    const int* __restrict__ ip = nidx + (size_t)point * NK;

    #pragma unroll
    for (int nk = 0; nk < NK; ++nk) {
        const int idx = ip[nk];                       // broadcast load
        const float cx = coords_in[cbase + idx];      // broadcast gather
        const float cy = coords_in[B * N_IN + cbase + idx];
        const float dx = cox - cx;
        const float dy = coy - cy;
        const float d2 = dx * dx + dy * dy;

        // feature gather: 8 lanes x float4 = contiguous 128B line
        const float4 f = *reinterpret_cast<const float4*>(
            x + (size_t)(cbase + idx) * D + q * 4);

        const float w0 = __expf(-d2 * s0);
        const float w1 = __expf(-d2 * s1);
        const float w2 = __expf(-d2 * s2);
        const float w3 = __expf(-d2 * s3);

        num.x += w0 * f.x;  den.x += w0;
        num.y += w1 * f.y;  den.y += w1;
        num.z += w2 * f.z;  den.z += w2;
        num.w += w3 * f.w;  den.w += w3;
    }

    float4 o;
    o.x = num.x / (den.x + 1e-9f);
    o.y = num.y / (den.y + 1e-9f);
    o.z = num.z / (den.z + 1e-9f);
    o.w = num.w / (den.w + 1e-9f);

    *reinterpret_cast<float4*>(out + (size_t)point * D + q * 4) = o;
}

extern "C" void kernel_launch(void* const* d_in, const int* in_sizes, int n_in,
                              void* d_out, int out_size, void* d_ws, size_t ws_size,
                              hipStream_t stream) {
    const float* x      = (const float*)d_in[0];  // x_level_in
    const float* cin    = (const float*)d_in[1];  // coords_in
    const float* cout_  = (const float*)d_in[2];  // coords_out
    const float* sigma  = (const float*)d_in[3];  // sigma
    const int*   nidx   = (const int*)  d_in[4];  // neighbor_idx
    float*       outp   = (float*)d_out;

    const int threads = P * 8;               // 4,194,304
    const int block   = 256;
    const int grid    = threads / block;     // 16384
    projection_kernel<<<grid, block, 0, stream>>>(x, cin, cout_, sigma, nidx, outp);
}